// Round 17
// baseline (182.408 us; speedup 1.0000x reference)
//
#include <hip/hip_runtime.h>
#include <stdint.h>

typedef unsigned short u16;
typedef unsigned int u32;
using short8 = __attribute__((ext_vector_type(8))) short;   // 8 x bf16 (4 VGPRs)
using f32x4  = __attribute__((ext_vector_type(4))) float;
using f32x16 = __attribute__((ext_vector_type(16))) float;  // 32x32 MFMA acc

typedef __attribute__((address_space(1))) unsigned int gu32;
typedef __attribute__((address_space(3))) unsigned int lu32;

// async 16B global->LDS. LDS dst = wave-uniform base + lane*16 (m97/m104).
__device__ __forceinline__ void gl2lds16(const u16* g, u16* lds_wave_base) {
    __builtin_amdgcn_global_load_lds(
        (gu32*)(uintptr_t)(const void*)g,
        (lu32*)(uint32_t)(uintptr_t)(void*)lds_wave_base,
        16, 0, 0);
}

__device__ inline float bf2f(u16 u) {
    union { unsigned int i; float f; } v;
    v.i = ((unsigned int)u) << 16;
    return v.f;
}
__device__ inline u16 f2bf(float f) {          // RNE
    union { float f; unsigned int i; } v;
    v.f = f;
    unsigned int x = v.i;
    return (u16)((x + 0x7fffu + ((x >> 16) & 1u)) >> 16);
}
__device__ inline u32 f2bf_trunc_u32(float f) { // truncate, value in low 16
    union { float f; unsigned int i; } v;
    v.f = f;
    return v.i >> 16;
}

// ---------------------------------------------------------------------------
// Kernel 1 (prep, single launch): z=0..3 transpose+cvt the 4 weight matrices;
// z=4 fills the RoPE (cos,sin) fp32 table; z=5..8 convert x fp32->bf16.
// ---------------------------------------------------------------------------
__global__ __launch_bounds__(256) void prep(
    const float* __restrict__ x, u16* __restrict__ xb,
    const float* __restrict__ w0, const float* __restrict__ w1,
    const float* __restrict__ w2, const float* __restrict__ w3,
    u16* __restrict__ t0, u16* __restrict__ t1,
    u16* __restrict__ t2, u16* __restrict__ t3,
    float2* __restrict__ tab)
{
    int tx = threadIdx.x, ty = threadIdx.y;              // (32, 8)
    int tid = ty * 32 + tx;
    int z = blockIdx.z;
    if (z == 4) {
        int bidx = blockIdx.y * 32 + blockIdx.x;
        if (bidx < 256) {
            int idx = bidx * 256 + tid;                  // 0..65535
            int pos = idx >> 5, pi = idx & 31;
            const float l2_10000_over_32 = 0.41524101186f;   // log2(10000)/32
            float ang = (float)pos *
                __builtin_amdgcn_exp2f(-(float)pi * l2_10000_over_32);
            float sn, cs;
            __sincosf(ang, &sn, &cs);
            tab[idx] = make_float2(cs, sn);
        }
        return;
    }
    if (z >= 5) {
        int i = (((z - 5) * 1024 + blockIdx.y * 32 + blockIdx.x) * 256 + tid) * 4;
        float4 v = *(const float4*)(x + i);
        ushort4 o;
        o.x = f2bf(v.x); o.y = f2bf(v.y); o.z = f2bf(v.z); o.w = f2bf(v.w);
        *(ushort4*)(xb + i) = o;
        return;
    }
    __shared__ u16 tile[32][33];
    const float* src; u16* dst;
    switch (z) {
        case 0:  src = w0; dst = t0; break;
        case 1:  src = w1; dst = t1; break;
        case 2:  src = w2; dst = t2; break;
        default: src = w3; dst = t3; break;
    }
    int c0 = blockIdx.x * 32, r0 = blockIdx.y * 32;
    #pragma unroll
    for (int i = 0; i < 4; i++)
        tile[ty + i * 8][tx] = f2bf(src[(size_t)(r0 + ty + i * 8) * 1024 + c0 + tx]);
    __syncthreads();
    #pragma unroll
    for (int i = 0; i < 4; i++)
        dst[(size_t)(c0 + ty + i * 8) * 1024 + r0 + tx] = tile[tx][ty + i * 8];
}

// ---------------------------------------------------------------------------
// Kernel 2a: fused QKV GEMM v2 — BN=64, grid (48,32) ~ 5-6 blocks/CU (R10:
//  -3.7us wall vs 3 blocks/CU). V epilogue STORES PERMUTED POSITIONS:
//  within each 16-pos group, order [0-3, 8-11, 4-7, 12-15] (swap the two
//  bits of quad). This makes attn's PV A-fragment lane-local — VT consumers
//  must use the permuted key order. BK stays 64 here: BK=128 would cut
//  occupancy 5-6 -> 3 blocks/CU (48 KB LDS) — not the proven direction.
// ---------------------------------------------------------------------------
__global__ __launch_bounds__(256) void gemm_qkv(
    const u16* __restrict__ A, const u16* __restrict__ Bt,
    const float2* __restrict__ ropetab,
    u16* __restrict__ Qb, u16* __restrict__ Kb, u16* __restrict__ VT)
{
    __shared__ __align__(16) char smem[24576];           // 24 KB pool
    u16* As = (u16*)smem;                                // 128x64 (16 KB)
    u16* Bs = (u16*)(smem + 16384);                      // 64x64  (8 KB)

    const int tid  = threadIdx.x;
    const int lane = tid & 63;
    const int wid  = tid >> 6;
    const int quad = lane >> 4;
    const int l15  = lane & 15;
    const int wm   = wid >> 1, wn = wid & 1;

    const int m0 = blockIdx.y * 128;
    const int n0 = blockIdx.x * 64;           // 0..3008, global stacked col
    const int mat = n0 >> 10;                 // 0=Q 1=K 2=V
    const int ln0 = n0 & 1023;                // col within that matrix (64-al)

    f32x4 acc[4][2] = {};

    for (int k0 = 0; k0 < 1024; k0 += 64) {
        #pragma unroll
        for (int it = 0; it < 4; it++) {             // A: 1024 chunks
            int c   = it * 256 + tid;
            int row = c >> 3;
            int col = ((c & 7) ^ (row & 7)) * 8;
            gl2lds16(&A[(size_t)(m0 + row) * 1024 + k0 + col],
                     &As[(size_t)(it * 256 + wid * 64) * 8]);
        }
        #pragma unroll
        for (int it = 0; it < 2; it++) {             // B: 512 chunks (64 rows)
            int c   = it * 256 + tid;
            int row = c >> 3;
            int col = ((c & 7) ^ (row & 7)) * 8;
            gl2lds16(&Bt[(size_t)(n0 + row) * 1024 + k0 + col],
                     &Bs[(size_t)(it * 256 + wid * 64) * 8]);
        }
        __syncthreads();

        #pragma unroll
        for (int s = 0; s < 2; s++) {            // two K=32 steps within BK=64
            short8 a[4], b[2];
            #pragma unroll
            for (int i = 0; i < 4; i++) {
                int ra = wm * 64 + i * 16 + l15;
                a[i] = *(const short8*)(&As[ra * 64 + (((s * 4 + quad) ^ (ra & 7)) * 8)]);
            }
            #pragma unroll
            for (int j = 0; j < 2; j++) {
                int rb = wn * 32 + j * 16 + l15;
                b[j] = *(const short8*)(&Bs[rb * 64 + (((s * 4 + quad) ^ (rb & 7)) * 8)]);
            }
            #pragma unroll
            for (int i = 0; i < 4; i++)
                #pragma unroll
                for (int j = 0; j < 2; j++)
                    acc[i][j] = __builtin_amdgcn_mfma_f32_16x16x32_bf16(a[i], b[j], acc[i][j], 0, 0, 0);
        }
        __syncthreads();
    }

    if (mat < 2) {
        u16* C = (mat == 0) ? Qb : Kb;
        const float scale = (mat == 0) ? (0.03125f * 1.44269504f) : 1.0f;
        const int odd = l15 & 1;
        #pragma unroll
        for (int i = 0; i < 4; i++)
            #pragma unroll
            for (int j = 0; j < 2; j++)
                #pragma unroll
                for (int r = 0; r < 4; r++) {
                    int lrow = wm * 64 + i * 16 + quad * 4 + r;
                    int col  = ln0 + wn * 32 + j * 16 + l15;
                    int pos  = (m0 + lrow) & 2047;
                    float v  = acc[i][j][r] * scale;
                    float vp = __shfl_xor(v, 1);     // partner column
                    float2 sc = ropetab[pos * 32 + ((col & 63) >> 1)];
                    float outv = odd ? (v * sc.x + vp * sc.y)
                                     : (v * sc.x - vp * sc.y);
                    C[(size_t)(m0 + lrow) * 1024 + col] = f2bf(outv);
                }
    } else {
        // V: bounce through LDS transposed WITH PERMUTED POSITIONS, then
        // coalesced writes to VT. Block covers exactly ONE head.
        u16* T = (u16*)smem;                    // 64 ch x 136 (pad) pos rows
        __syncthreads();                        // all waves done with As/Bs
        const int qp = ((quad & 1) << 1) | (quad >> 1);   // bit-swap
        #pragma unroll
        for (int i = 0; i < 4; i++)
            #pragma unroll
            for (int j = 0; j < 2; j++)
                #pragma unroll
                for (int r = 0; r < 4; r++) {
                    int prow = wm * 64 + i * 16 + qp * 4 + r;     // permuted
                    int lcol = wn * 32 + j * 16 + l15;            // ch 0..63
                    T[lcol * 136 + prow] = f2bf(acc[i][j][r]);
                }
        __syncthreads();
        int bb2 = m0 >> 11, pos0 = m0 & 2047, h2 = ln0 >> 6;
        #pragma unroll
        for (int itc = 0; itc < 4; itc++) {
            int c  = itc * 256 + tid;           // 0..1023 chunks of 8 u16
            int ch = c >> 4;                    // 0..63
            int px = (c & 15) * 8;              // 0..120
            size_t dst = ((size_t)(bb2 * 16 + h2) * 64 + ch) * 2048
                         + pos0 + px;
            *(uint4*)(&VT[dst]) = *(const uint4*)(&T[ch * 136 + px]);
        }
    }
}

// ---------------------------------------------------------------------------
// Kernel 2b: out-projection GEMM v4 — BK 64->128 (drain amortization).
//  v3 (R14): 16 K-steps, each with full vmcnt(0) drain + 2 barriers, only
//  ~8 MFMA/wave/step — per-step cost is the ~400cy drain, not compute.
//  v4: BK=128 halves the drain count (8 steps); LDS 16->32 KB which KEEPS
//  4 blocks/CU (160/32 = 5) — unlike m132's 64 KB occupancy collapse.
//  Same total VMEM (8 gl2lds16/thread/step x 8 steps). K-chunk swizzle is
//  the 16-chunk ^(row&15) pattern proven conflict-free in attn's VTs;
//  fragment chunk = (s*4+quad)^(ra&15), s=0..3. Grid/epilogue unchanged.
// ---------------------------------------------------------------------------
__global__ __launch_bounds__(256) void gemm_out(
    const u16* __restrict__ A, const u16* __restrict__ Bt, float* __restrict__ C)
{
    __shared__ __align__(16) u16 As[64 * 128];   // 16 KB
    __shared__ __align__(16) u16 Bs[64 * 128];   // 16 KB

    const int tid  = threadIdx.x;
    const int lane = tid & 63;
    const int wid  = tid >> 6;
    const int quad = lane >> 4;
    const int l15  = lane & 15;
    const int wm   = wid >> 1, wn = wid & 1;

    const int m0 = blockIdx.y * 64;
    const int n0 = blockIdx.x * 64;

    f32x4 acc[2][2] = {};

    for (int k0 = 0; k0 < 1024; k0 += 128) {
        #pragma unroll
        for (int it = 0; it < 4; it++) {             // A: 1024 chunks (64x128)
            int c   = it * 256 + tid;
            int row = c >> 4;                        // 16 chunks per row
            int col = ((c & 15) ^ (row & 15)) * 8;   // swizzled source chunk
            gl2lds16(&A[(size_t)(m0 + row) * 1024 + k0 + col],
                     &As[(size_t)(it * 256 + wid * 64) * 8]);
        }
        #pragma unroll
        for (int it = 0; it < 4; it++) {             // B: 1024 chunks (64x128)
            int c   = it * 256 + tid;
            int row = c >> 4;
            int col = ((c & 15) ^ (row & 15)) * 8;
            gl2lds16(&Bt[(size_t)(n0 + row) * 1024 + k0 + col],
                     &Bs[(size_t)(it * 256 + wid * 64) * 8]);
        }
        __syncthreads();

        #pragma unroll
        for (int s = 0; s < 4; s++) {            // four K=32 steps in BK=128
            short8 a[2], b[2];
            #pragma unroll
            for (int i = 0; i < 2; i++) {
                int ra = wm * 32 + i * 16 + l15;
                a[i] = *(const short8*)(&As[ra * 128 + (((s * 4 + quad) ^ (ra & 15)) * 8)]);
            }
            #pragma unroll
            for (int j = 0; j < 2; j++) {
                int rb = wn * 32 + j * 16 + l15;
                b[j] = *(const short8*)(&Bs[rb * 128 + (((s * 4 + quad) ^ (rb & 15)) * 8)]);
            }
            #pragma unroll
            for (int i = 0; i < 2; i++)
                #pragma unroll
                for (int j = 0; j < 2; j++)
                    acc[i][j] = __builtin_amdgcn_mfma_f32_16x16x32_bf16(a[i], b[j], acc[i][j], 0, 0, 0);
        }
        __syncthreads();
    }

    #pragma unroll
    for (int i = 0; i < 2; i++)
        #pragma unroll
        for (int j = 0; j < 2; j++)
            #pragma unroll
            for (int r = 0; r < 4; r++) {
                int row = m0 + wm * 32 + i * 16 + quad * 4 + r;
                int col = n0 + wn * 32 + j * 16 + l15;
                C[(size_t)row * 1024 + col] = acc[i][j][r];
            }
}

// ---------------------------------------------------------------------------
// Kernel 4: flash attention v17 (FINAL — best measured 46.0us, reproduced).
//  Arc ledger (all closed):
//   - key-split occupancy (v9/v18/v19): fixed per-block K/V staging cost
//     beats the latency-hiding gain at any blocks/CU. Dead.
//   - LDS double-buffer (v12 big-block, v20 lambda-pointer): both regressed
//     hard; this kernel needs compile-time-folded LDS addressing and the
//     cross-block phase overlap of 2 independent 256-thr blocks/CU.
//   - permlane/cvt_pk register-P (v10/v11): unverifiable lane semantics,
//     2 correctness failures. Replaced by the permuted-VT trick (R11, -9us)
//     which needs NO cross-lane ops at all.
//  Techniques in force: T14 named-reg prefetch staging (R7, spill-proofed
//  via named uint4 + launch_bounds(256,2)), in-register softmax (R8),
//  permuted-VT lane-local PV A-frags (R11), Ks pad-68 + linear VTs swizzle
//  (0 bank conflicts), setprio around MFMA clusters.
// ---------------------------------------------------------------------------
__global__ __launch_bounds__(256, 2) void attn(
    const u16* __restrict__ Q, const u16* __restrict__ Kb,
    const u16* __restrict__ VT, u16* __restrict__ Y)
{
    __shared__ __align__(16) u16 Ks [128 * 68];   // row=key (pad 4), swizzled
    __shared__ __align__(16) u16 VTs[64 * 128];   // row=ch, 16 chunks ^(r&15)

    const int tid  = threadIdx.x;
    const int lane = tid & 63, wid = tid >> 6;    // wid 0..3
    const int l31  = lane & 31, hi = lane >> 5;   // hi = 0/1

    const int bh = blockIdx.x;        // 0..31  (XCD-locality: fast axis)
    const int qt = blockIdx.y;        // 0..15, 128 q-rows each
    const int bb = bh >> 4, h = bh & 15;

    const size_t base = ((size_t)bb * 2048) * 1024 + (size_t)h * 64;

    // Q B-fragments (B[n=qrow][k=ch]: n = lane&31, ch = hi*8 + j + 16s)
    short8 qf[4];
    {
        const u16* qp = Q + base
                      + ((size_t)qt * 128 + wid * 32 + l31) * 1024 + hi * 8;
        #pragma unroll
        for (int s = 0; s < 4; s++)
            qf[s] = *(const short8*)(qp + s * 16);
    }

    // Per-thread staging geometry. chunk c = it*256 + tid;
    // K: rk=c>>3, src col ((c&7)^(rk&7))*8; LDS dst row rk*68 + (c&7)*8.
    // V: rv=c>>4, src col ((c&15)^(rv&15))*8; LDS dst linear chunk c.
    const int c0 = tid,        c1 = 256 + tid,
              c2 = 512 + tid,  c3 = 768 + tid;
    const int rk0 = c0 >> 3, ck0 = ((c0 & 7) ^ (rk0 & 7)) * 8;
    const int rk1 = c1 >> 3, ck1 = ((c1 & 7) ^ (rk1 & 7)) * 8;
    const int rk2 = c2 >> 3, ck2 = ((c2 & 7) ^ (rk2 & 7)) * 8;
    const int rk3 = c3 >> 3, ck3 = ((c3 & 7) ^ (rk3 & 7)) * 8;
    const int rv0 = c0 >> 4, cv0 = ((c0 & 15) ^ (rv0 & 15)) * 8;
    const int rv1 = c1 >> 4, cv1 = ((c1 & 15) ^ (rv1 & 15)) * 8;
    const int rv2 = c2 >> 4, cv2 = ((c2 & 15) ^ (rv2 & 15)) * 8;
    const int rv3 = c3 >> 4, cv3 = ((c3 & 15) ^ (rv3 & 15)) * 8;
    const int dK0 = rk0 * 68 + (c0 & 7) * 8, dK1 = rk1 * 68 + (c1 & 7) * 8;
    const int dK2 = rk2 * 68 + (c2 & 7) * 8, dK3 = rk3 * 68 + (c3 & 7) * 8;
    const u16* pK = Kb + base;                        // + (j0+rk)*1024 + ck
    const u16* pV = VT + ((size_t)bh * 64) * 2048;    // + rv*2048 + j0 + cv
    const size_t oK0 = (size_t)rk0 * 1024 + ck0, oK1 = (size_t)rk1 * 1024 + ck1;
    const size_t oK2 = (size_t)rk2 * 1024 + ck2, oK3 = (size_t)rk3 * 1024 + ck3;
    const size_t oV0 = (size_t)rv0 * 2048 + cv0, oV1 = (size_t)rv1 * 2048 + cv1;
    const size_t oV2 = (size_t)rv2 * 2048 + cv2, oV3 = (size_t)rv3 * 2048 + cv3;

    uint4 k0r, k1r, k2r, k3r, v0r, v1r, v2r, v3r;   // named: not demotable
#define LOADREGS(J0)                                                        \
    do {                                                                    \
        const size_t jk = (size_t)(J0) * 1024;                              \
        k0r = *(const uint4*)(pK + jk + oK0);                               \
        k1r = *(const uint4*)(pK + jk + oK1);                               \
        k2r = *(const uint4*)(pK + jk + oK2);                               \
        k3r = *(const uint4*)(pK + jk + oK3);                               \
        v0r = *(const uint4*)(pV + (J0) + oV0);                             \
        v1r = *(const uint4*)(pV + (J0) + oV1);                             \
        v2r = *(const uint4*)(pV + (J0) + oV2);                             \
        v3r = *(const uint4*)(pV + (J0) + oV3);                             \
    } while (0)

    f32x16 o0 = {}, o1 = {};
    float lsum = 0.0f;

    LOADREGS(0);                      // prologue: tile 0 in flight to regs

    for (int j0 = 0; j0 < 2048; j0 += 128) {
        __syncthreads();   // prior tile's fragment reads complete
        *(uint4*)(&Ks [dK0]) = k0r;                   // compiler inserts
        *(uint4*)(&Ks [dK1]) = k1r;                   // vmcnt waits
        *(uint4*)(&Ks [dK2]) = k2r;
        *(uint4*)(&Ks [dK3]) = k3r;
        *(uint4*)(&VTs[(0 * 256 + tid) * 8]) = v0r;
        *(uint4*)(&VTs[(1 * 256 + tid) * 8]) = v1r;
        *(uint4*)(&VTs[(2 * 256 + tid) * 8]) = v2r;
        *(uint4*)(&VTs[(3 * 256 + tid) * 8]) = v3r;
        if (j0 + 128 < 2048)
            LOADREGS(j0 + 128);       // next tile's loads fly under compute
        __syncthreads();   // LDS writes visible to all waves

        // S^T = K * Q^T: 4 stripes of 32 keys. A = K-frag (m=key lane&31,
        // ch = hi*8+16s), B = Q-frag (regs). C col = qrow, row = key.
        f32x16 st[4];
        #pragma unroll
        for (int t = 0; t < 4; t++) {
            int key = t * 32 + l31;
            f32x16 z = {};
            __builtin_amdgcn_s_setprio(1);
            #pragma unroll
            for (int s = 0; s < 4; s++) {
                int chunk = ((2 * s + hi) ^ (key & 7)) * 8;
                short8 kf = *(const short8*)(&Ks[key * 68 + chunk]);
                z = __builtin_amdgcn_mfma_f32_32x32x16_bf16(kf, qf[s], z, 0, 0, 0);
            }
            __builtin_amdgcn_s_setprio(0);
            st[t] = z;
        }

        // softmax fully in registers: X/Y[t][g] pack keys (t*32+g*8+4hi)+0..3
        // for qrow = l31 (bit-identical values to the old Ps path).
        u32 X[4][4], Y[4][4];
        #pragma unroll
        for (int t = 0; t < 4; t++)
            #pragma unroll
            for (int g = 0; g < 4; g++) {
                float p0 = __builtin_amdgcn_exp2f(st[t][4 * g + 0]);
                float p1 = __builtin_amdgcn_exp2f(st[t][4 * g + 1]);
                float p2 = __builtin_amdgcn_exp2f(st[t][4 * g + 2]);
                float p3 = __builtin_amdgcn_exp2f(st[t][4 * g + 3]);
                lsum += (p0 + p1) + (p2 + p3);
                X[t][g] = f2bf_trunc_u32(p0) | (f2bf_trunc_u32(p1) << 16);
                Y[t][g] = f2bf_trunc_u32(p2) | (f2bf_trunc_u32(p3) << 16);
            }

        // PV: O[qrow][ch] += P * V over 8 sixteen-key chunks c16 (keys
        // 16*c16..+15). VT's permuted key order ([0-3,8-11,4-7,12-15] per 16)
        // means B-chunk 2*c16+hi holds exactly keys {16c16+4hi+0..3,
        // 16c16+8+4hi+0..3} — the keys THIS lane's X/Y regs hold. A-frag is
        // lane-local and hi-independent: {X[t][2u],Y[t][2u],X[t][2u+1],
        // Y[t][2u+1]} with t=c16>>1, u=c16&1. No shuffles.
        #pragma unroll
        for (int c16 = 0; c16 < 8; ++c16) {
            const int t = c16 >> 1, u = c16 & 1;
            union { u32 u4[4]; short8 s8; } pk;
            pk.u4[0] = X[t][2 * u];        // keys 16c16+4hi+0,1
            pk.u4[1] = Y[t][2 * u];        // keys 16c16+4hi+2,3
            pk.u4[2] = X[t][2 * u + 1];    // keys 16c16+8+4hi+0,1
            pk.u4[3] = Y[t][2 * u + 1];    // keys 16c16+8+4hi+2,3
            const int kch = 2 * c16 + hi;             // VTs 8-u16 chunk
            short8 v0 = *(const short8*)(&VTs[l31 * 128 + ((kch ^ (l31 & 15)) * 8)]);
            short8 v1 = *(const short8*)(&VTs[(32 + l31) * 128 + ((kch ^ ((32 + l31) & 15)) * 8)]);
            __builtin_amdgcn_s_setprio(1);
            o0 = __builtin_amdgcn_mfma_f32_32x32x16_bf16(pk.s8, v0, o0, 0, 0, 0);
            o1 = __builtin_amdgcn_mfma_f32_32x32x16_bf16(pk.s8, v1, o1, 0, 0, 0);
            __builtin_amdgcn_s_setprio(0);
        }
    }
#undef LOADREGS

    // row-sum: lane holds all partials for qrow = lane&31 (S^T col) ->
    // one cross-half reduce, then broadcast per-reg via shfl.
    lsum += __shfl_xor(lsum, 32);
    float linv = 1.0f / lsum;

    size_t qrow0 = (size_t)qt * 128 + wid * 32;
    #pragma unroll
    for (int half = 0; half < 2; half++) {
        f32x16 o = half ? o1 : o0;
        #pragma unroll
        for (int reg = 0; reg < 16; reg++) {
            int qrow = (reg & 3) + 8 * (reg >> 2) + 4 * hi;   // C/D row (m74)
            float nv = o[reg] * __shfl(linv, qrow);
            Y[base + (qrow0 + qrow) * 1024 + half * 32 + l31] = f2bf(nv);
        }
    }
}

// ---------------------------------------------------------------------------
extern "C" void kernel_launch(void* const* d_in, const int* in_sizes, int n_in,
                              void* d_out, int out_size, void* d_ws, size_t ws_size,
                              hipStream_t stream)
{
    const float* x  = (const float*)d_in[0];
    const float* Wq = (const float*)d_in[1];
    const float* Wk = (const float*)d_in[2];
    const float* Wv = (const float*)d_in[3];
    const float* Wo = (const float*)d_in[4];
    float* out = (float*)d_out;

    char* ws = (char*)d_ws;
    u16*    xb    = (u16*)   (ws + (0ull  << 20));   // 8 MB
    u16*    WqkvT = (u16*)   (ws + (8ull  << 20));   // 6 MB stacked
    u16*    WoT   = (u16*)   (ws + (14ull << 20));   // 2 MB
    u16*    Qb    = (u16*)   (ws + (16ull << 20));   // 8 MB each
    u16*    Kb    = (u16*)   (ws + (24ull << 20));
    u16*    VTb   = (u16*)   (ws + (32ull << 20));   // V transposed per head
    u16*    Yb    = (u16*)   (ws + (40ull << 20));
    float2* tab   = (float2*)(ws + (48ull << 20));   // 512 KB rope table

    prep<<<dim3(32, 32, 9), dim3(32, 8), 0, stream>>>(
        x, xb, Wq, Wk, Wv, Wo,
        WqkvT, WqkvT + (1024ull * 1024), WqkvT + (2048ull * 1024), WoT, tab);
    gemm_qkv<<<dim3(48, 32), 256, 0, stream>>>(xb, WqkvT, tab, Qb, Kb, VTb);
    attn<<<dim3(32, 16), 256, 0, stream>>>(Qb, Kb, VTb, Yb);
    gemm_out<<<dim3(16, 64), 256, 0, stream>>>(Yb, WoT, out);
}

// Round 18
// 178.602 us; speedup vs baseline: 1.0213x; 1.0213x over previous
//
#include <hip/hip_runtime.h>
#include <stdint.h>

typedef unsigned short u16;
typedef unsigned int u32;
using short8 = __attribute__((ext_vector_type(8))) short;   // 8 x bf16 (4 VGPRs)
using f32x4  = __attribute__((ext_vector_type(4))) float;
using f32x16 = __attribute__((ext_vector_type(16))) float;  // 32x32 MFMA acc

typedef __attribute__((address_space(1))) unsigned int gu32;
typedef __attribute__((address_space(3))) unsigned int lu32;

// async 16B global->LDS. LDS dst = wave-uniform base + lane*16 (m97/m104).
__device__ __forceinline__ void gl2lds16(const u16* g, u16* lds_wave_base) {
    __builtin_amdgcn_global_load_lds(
        (gu32*)(uintptr_t)(const void*)g,
        (lu32*)(uint32_t)(uintptr_t)(void*)lds_wave_base,
        16, 0, 0);
}

__device__ inline float bf2f(u16 u) {
    union { unsigned int i; float f; } v;
    v.i = ((unsigned int)u) << 16;
    return v.f;
}
__device__ inline u16 f2bf(float f) {          // RNE
    union { float f; unsigned int i; } v;
    v.f = f;
    unsigned int x = v.i;
    return (u16)((x + 0x7fffu + ((x >> 16) & 1u)) >> 16);
}
__device__ inline u32 f2bf_trunc_u32(float f) { // truncate, value in low 16
    union { float f; unsigned int i; } v;
    v.f = f;
    return v.i >> 16;
}

// ---------------------------------------------------------------------------
// Kernel 1 (prep, single launch): z=0..3 transpose+cvt the 4 weight matrices;
// z=4 fills the RoPE (cos,sin) fp32 table; z=5..8 convert x fp32->bf16.
// ---------------------------------------------------------------------------
__global__ __launch_bounds__(256) void prep(
    const float* __restrict__ x, u16* __restrict__ xb,
    const float* __restrict__ w0, const float* __restrict__ w1,
    const float* __restrict__ w2, const float* __restrict__ w3,
    u16* __restrict__ t0, u16* __restrict__ t1,
    u16* __restrict__ t2, u16* __restrict__ t3,
    float2* __restrict__ tab)
{
    int tx = threadIdx.x, ty = threadIdx.y;              // (32, 8)
    int tid = ty * 32 + tx;
    int z = blockIdx.z;
    if (z == 4) {
        int bidx = blockIdx.y * 32 + blockIdx.x;
        if (bidx < 256) {
            int idx = bidx * 256 + tid;                  // 0..65535
            int pos = idx >> 5, pi = idx & 31;
            const float l2_10000_over_32 = 0.41524101186f;   // log2(10000)/32
            float ang = (float)pos *
                __builtin_amdgcn_exp2f(-(float)pi * l2_10000_over_32);
            float sn, cs;
            __sincosf(ang, &sn, &cs);
            tab[idx] = make_float2(cs, sn);
        }
        return;
    }
    if (z >= 5) {
        int i = (((z - 5) * 1024 + blockIdx.y * 32 + blockIdx.x) * 256 + tid) * 4;
        float4 v = *(const float4*)(x + i);
        ushort4 o;
        o.x = f2bf(v.x); o.y = f2bf(v.y); o.z = f2bf(v.z); o.w = f2bf(v.w);
        *(ushort4*)(xb + i) = o;
        return;
    }
    __shared__ u16 tile[32][33];
    const float* src; u16* dst;
    switch (z) {
        case 0:  src = w0; dst = t0; break;
        case 1:  src = w1; dst = t1; break;
        case 2:  src = w2; dst = t2; break;
        default: src = w3; dst = t3; break;
    }
    int c0 = blockIdx.x * 32, r0 = blockIdx.y * 32;
    #pragma unroll
    for (int i = 0; i < 4; i++)
        tile[ty + i * 8][tx] = f2bf(src[(size_t)(r0 + ty + i * 8) * 1024 + c0 + tx]);
    __syncthreads();
    #pragma unroll
    for (int i = 0; i < 4; i++)
        dst[(size_t)(c0 + ty + i * 8) * 1024 + r0 + tx] = tile[tx][ty + i * 8];
}

// ---------------------------------------------------------------------------
// Kernel 2a: fused QKV GEMM v2 — BN=64, grid (48,32) ~ 5-6 blocks/CU (R10:
//  -3.7us wall vs 3 blocks/CU). V epilogue STORES PERMUTED POSITIONS:
//  within each 16-pos group, order [0-3, 8-11, 4-7, 12-15] (swap the two
//  bits of quad). This makes attn's PV A-fragment lane-local — VT consumers
//  must use the permuted key order.
// ---------------------------------------------------------------------------
__global__ __launch_bounds__(256) void gemm_qkv(
    const u16* __restrict__ A, const u16* __restrict__ Bt,
    const float2* __restrict__ ropetab,
    u16* __restrict__ Qb, u16* __restrict__ Kb, u16* __restrict__ VT)
{
    __shared__ __align__(16) char smem[24576];           // 24 KB pool
    u16* As = (u16*)smem;                                // 128x64 (16 KB)
    u16* Bs = (u16*)(smem + 16384);                      // 64x64  (8 KB)

    const int tid  = threadIdx.x;
    const int lane = tid & 63;
    const int wid  = tid >> 6;
    const int quad = lane >> 4;
    const int l15  = lane & 15;
    const int wm   = wid >> 1, wn = wid & 1;

    const int m0 = blockIdx.y * 128;
    const int n0 = blockIdx.x * 64;           // 0..3008, global stacked col
    const int mat = n0 >> 10;                 // 0=Q 1=K 2=V
    const int ln0 = n0 & 1023;                // col within that matrix (64-al)

    f32x4 acc[4][2] = {};

    for (int k0 = 0; k0 < 1024; k0 += 64) {
        #pragma unroll
        for (int it = 0; it < 4; it++) {             // A: 1024 chunks
            int c   = it * 256 + tid;
            int row = c >> 3;
            int col = ((c & 7) ^ (row & 7)) * 8;
            gl2lds16(&A[(size_t)(m0 + row) * 1024 + k0 + col],
                     &As[(size_t)(it * 256 + wid * 64) * 8]);
        }
        #pragma unroll
        for (int it = 0; it < 2; it++) {             // B: 512 chunks (64 rows)
            int c   = it * 256 + tid;
            int row = c >> 3;
            int col = ((c & 7) ^ (row & 7)) * 8;
            gl2lds16(&Bt[(size_t)(n0 + row) * 1024 + k0 + col],
                     &Bs[(size_t)(it * 256 + wid * 64) * 8]);
        }
        __syncthreads();

        #pragma unroll
        for (int s = 0; s < 2; s++) {            // two K=32 steps within BK=64
            short8 a[4], b[2];
            #pragma unroll
            for (int i = 0; i < 4; i++) {
                int ra = wm * 64 + i * 16 + l15;
                a[i] = *(const short8*)(&As[ra * 64 + (((s * 4 + quad) ^ (ra & 7)) * 8)]);
            }
            #pragma unroll
            for (int j = 0; j < 2; j++) {
                int rb = wn * 32 + j * 16 + l15;
                b[j] = *(const short8*)(&Bs[rb * 64 + (((s * 4 + quad) ^ (rb & 7)) * 8)]);
            }
            #pragma unroll
            for (int i = 0; i < 4; i++)
                #pragma unroll
                for (int j = 0; j < 2; j++)
                    acc[i][j] = __builtin_amdgcn_mfma_f32_16x16x32_bf16(a[i], b[j], acc[i][j], 0, 0, 0);
        }
        __syncthreads();
    }

    if (mat < 2) {
        u16* C = (mat == 0) ? Qb : Kb;
        const float scale = (mat == 0) ? (0.03125f * 1.44269504f) : 1.0f;
        const int odd = l15 & 1;
        #pragma unroll
        for (int i = 0; i < 4; i++)
            #pragma unroll
            for (int j = 0; j < 2; j++)
                #pragma unroll
                for (int r = 0; r < 4; r++) {
                    int lrow = wm * 64 + i * 16 + quad * 4 + r;
                    int col  = ln0 + wn * 32 + j * 16 + l15;
                    int pos  = (m0 + lrow) & 2047;
                    float v  = acc[i][j][r] * scale;
                    float vp = __shfl_xor(v, 1);     // partner column
                    float2 sc = ropetab[pos * 32 + ((col & 63) >> 1)];
                    float outv = odd ? (v * sc.x + vp * sc.y)
                                     : (v * sc.x - vp * sc.y);
                    C[(size_t)(m0 + lrow) * 1024 + col] = f2bf(outv);
                }
    } else {
        // V: bounce through LDS transposed WITH PERMUTED POSITIONS, then
        // coalesced writes to VT. Block covers exactly ONE head.
        u16* T = (u16*)smem;                    // 64 ch x 136 (pad) pos rows
        __syncthreads();                        // all waves done with As/Bs
        const int qp = ((quad & 1) << 1) | (quad >> 1);   // bit-swap
        #pragma unroll
        for (int i = 0; i < 4; i++)
            #pragma unroll
            for (int j = 0; j < 2; j++)
                #pragma unroll
                for (int r = 0; r < 4; r++) {
                    int prow = wm * 64 + i * 16 + qp * 4 + r;     // permuted
                    int lcol = wn * 32 + j * 16 + l15;            // ch 0..63
                    T[lcol * 136 + prow] = f2bf(acc[i][j][r]);
                }
        __syncthreads();
        int bb2 = m0 >> 11, pos0 = m0 & 2047, h2 = ln0 >> 6;
        #pragma unroll
        for (int itc = 0; itc < 4; itc++) {
            int c  = itc * 256 + tid;           // 0..1023 chunks of 8 u16
            int ch = c >> 4;                    // 0..63
            int px = (c & 15) * 8;              // 0..120
            size_t dst = ((size_t)(bb2 * 16 + h2) * 64 + ch) * 2048
                         + pos0 + px;
            *(uint4*)(&VT[dst]) = *(const uint4*)(&T[ch * 136 + px]);
        }
    }
}

// ---------------------------------------------------------------------------
// Kernel 2b: out-projection GEMM v3 — BM=64/BN=64, grid (16,64) = 1024 blocks
// = 4 blocks/CU (R14). LDS 16 KB, wave tile 32x32, acc[2][2]. BK stays 64:
// R17 measured BK=128 as null (drain count is not this kernel's binding
// constraint) — reverted to the twice-reproduced best config.
// ---------------------------------------------------------------------------
__global__ __launch_bounds__(256) void gemm_out(
    const u16* __restrict__ A, const u16* __restrict__ Bt, float* __restrict__ C)
{
    __shared__ __align__(16) u16 As[64 * 64];    //  8 KB
    __shared__ __align__(16) u16 Bs[64 * 64];    //  8 KB

    const int tid  = threadIdx.x;
    const int lane = tid & 63;
    const int wid  = tid >> 6;
    const int quad = lane >> 4;
    const int l15  = lane & 15;
    const int wm   = wid >> 1, wn = wid & 1;

    const int m0 = blockIdx.y * 64;
    const int n0 = blockIdx.x * 64;

    f32x4 acc[2][2] = {};

    for (int k0 = 0; k0 < 1024; k0 += 64) {
        #pragma unroll
        for (int it = 0; it < 2; it++) {             // A: 512 chunks (64 rows)
            int c   = it * 256 + tid;
            int row = c >> 3;
            int col = ((c & 7) ^ (row & 7)) * 8;
            gl2lds16(&A[(size_t)(m0 + row) * 1024 + k0 + col],
                     &As[(size_t)(it * 256 + wid * 64) * 8]);
        }
        #pragma unroll
        for (int it = 0; it < 2; it++) {             // B: 512 chunks (64 rows)
            int c   = it * 256 + tid;
            int row = c >> 3;
            int col = ((c & 7) ^ (row & 7)) * 8;
            gl2lds16(&Bt[(size_t)(n0 + row) * 1024 + k0 + col],
                     &Bs[(size_t)(it * 256 + wid * 64) * 8]);
        }
        __syncthreads();

        #pragma unroll
        for (int s = 0; s < 2; s++) {
            short8 a[2], b[2];
            #pragma unroll
            for (int i = 0; i < 2; i++) {
                int ra = wm * 32 + i * 16 + l15;
                a[i] = *(const short8*)(&As[ra * 64 + (((s * 4 + quad) ^ (ra & 7)) * 8)]);
            }
            #pragma unroll
            for (int j = 0; j < 2; j++) {
                int rb = wn * 32 + j * 16 + l15;
                b[j] = *(const short8*)(&Bs[rb * 64 + (((s * 4 + quad) ^ (rb & 7)) * 8)]);
            }
            #pragma unroll
            for (int i = 0; i < 2; i++)
                #pragma unroll
                for (int j = 0; j < 2; j++)
                    acc[i][j] = __builtin_amdgcn_mfma_f32_16x16x32_bf16(a[i], b[j], acc[i][j], 0, 0, 0);
        }
        __syncthreads();
    }

    #pragma unroll
    for (int i = 0; i < 2; i++)
        #pragma unroll
        for (int j = 0; j < 2; j++)
            #pragma unroll
            for (int r = 0; r < 4; r++) {
                int row = m0 + wm * 32 + i * 16 + quad * 4 + r;
                int col = n0 + wn * 32 + j * 16 + l15;
                C[(size_t)row * 1024 + col] = acc[i][j][r];
            }
}

// ---------------------------------------------------------------------------
// Kernel 4: flash attention v17 (FINAL — 46.0us, reproduced twice).
//  Arc ledger (all closed with measured evidence):
//   - key-split occupancy (v9/v18/v19): fixed per-block K/V staging cost
//     beats latency-hiding at any blocks/CU. Dead.
//   - LDS double-buffer (v12 big-block, v20 lambda-pointer): both regressed
//     hard; this kernel needs compile-time-folded LDS addressing and the
//     cross-block phase overlap of 2 independent 256-thr blocks/CU.
//   - permlane/cvt_pk register-P (v10/v11): unverifiable lane semantics,
//     2 correctness failures. Replaced by the permuted-VT trick (R11, -9us)
//     which needs NO cross-lane ops at all.
//   - BK/drain amortization (R17, on gemm_out): null — these kernels are
//     staging-throughput bound, not drain-count bound.
//  Techniques in force: T14 named-reg prefetch staging (R7, spill-proofed
//  via named uint4 + launch_bounds(256,2)), in-register softmax (R8),
//  permuted-VT lane-local PV A-frags (R11), Ks pad-68 + linear VTs swizzle
//  (0 bank conflicts), setprio around MFMA clusters.
// ---------------------------------------------------------------------------
__global__ __launch_bounds__(256, 2) void attn(
    const u16* __restrict__ Q, const u16* __restrict__ Kb,
    const u16* __restrict__ VT, u16* __restrict__ Y)
{
    __shared__ __align__(16) u16 Ks [128 * 68];   // row=key (pad 4), swizzled
    __shared__ __align__(16) u16 VTs[64 * 128];   // row=ch, 16 chunks ^(r&15)

    const int tid  = threadIdx.x;
    const int lane = tid & 63, wid = tid >> 6;    // wid 0..3
    const int l31  = lane & 31, hi = lane >> 5;   // hi = 0/1

    const int bh = blockIdx.x;        // 0..31  (XCD-locality: fast axis)
    const int qt = blockIdx.y;        // 0..15, 128 q-rows each
    const int bb = bh >> 4, h = bh & 15;

    const size_t base = ((size_t)bb * 2048) * 1024 + (size_t)h * 64;

    // Q B-fragments (B[n=qrow][k=ch]: n = lane&31, ch = hi*8 + j + 16s)
    short8 qf[4];
    {
        const u16* qp = Q + base
                      + ((size_t)qt * 128 + wid * 32 + l31) * 1024 + hi * 8;
        #pragma unroll
        for (int s = 0; s < 4; s++)
            qf[s] = *(const short8*)(qp + s * 16);
    }

    // Per-thread staging geometry. chunk c = it*256 + tid;
    // K: rk=c>>3, src col ((c&7)^(rk&7))*8; LDS dst row rk*68 + (c&7)*8.
    // V: rv=c>>4, src col ((c&15)^(rv&15))*8; LDS dst linear chunk c.
    const int c0 = tid,        c1 = 256 + tid,
              c2 = 512 + tid,  c3 = 768 + tid;
    const int rk0 = c0 >> 3, ck0 = ((c0 & 7) ^ (rk0 & 7)) * 8;
    const int rk1 = c1 >> 3, ck1 = ((c1 & 7) ^ (rk1 & 7)) * 8;
    const int rk2 = c2 >> 3, ck2 = ((c2 & 7) ^ (rk2 & 7)) * 8;
    const int rk3 = c3 >> 3, ck3 = ((c3 & 7) ^ (rk3 & 7)) * 8;
    const int rv0 = c0 >> 4, cv0 = ((c0 & 15) ^ (rv0 & 15)) * 8;
    const int rv1 = c1 >> 4, cv1 = ((c1 & 15) ^ (rv1 & 15)) * 8;
    const int rv2 = c2 >> 4, cv2 = ((c2 & 15) ^ (rv2 & 15)) * 8;
    const int rv3 = c3 >> 4, cv3 = ((c3 & 15) ^ (rv3 & 15)) * 8;
    const int dK0 = rk0 * 68 + (c0 & 7) * 8, dK1 = rk1 * 68 + (c1 & 7) * 8;
    const int dK2 = rk2 * 68 + (c2 & 7) * 8, dK3 = rk3 * 68 + (c3 & 7) * 8;
    const u16* pK = Kb + base;                        // + (j0+rk)*1024 + ck
    const u16* pV = VT + ((size_t)bh * 64) * 2048;    // + rv*2048 + j0 + cv
    const size_t oK0 = (size_t)rk0 * 1024 + ck0, oK1 = (size_t)rk1 * 1024 + ck1;
    const size_t oK2 = (size_t)rk2 * 1024 + ck2, oK3 = (size_t)rk3 * 1024 + ck3;
    const size_t oV0 = (size_t)rv0 * 2048 + cv0, oV1 = (size_t)rv1 * 2048 + cv1;
    const size_t oV2 = (size_t)rv2 * 2048 + cv2, oV3 = (size_t)rv3 * 2048 + cv3;

    uint4 k0r, k1r, k2r, k3r, v0r, v1r, v2r, v3r;   // named: not demotable
#define LOADREGS(J0)                                                        \
    do {                                                                    \
        const size_t jk = (size_t)(J0) * 1024;                              \
        k0r = *(const uint4*)(pK + jk + oK0);                               \
        k1r = *(const uint4*)(pK + jk + oK1);                               \
        k2r = *(const uint4*)(pK + jk + oK2);                               \
        k3r = *(const uint4*)(pK + jk + oK3);                               \
        v0r = *(const uint4*)(pV + (J0) + oV0);                             \
        v1r = *(const uint4*)(pV + (J0) + oV1);                             \
        v2r = *(const uint4*)(pV + (J0) + oV2);                             \
        v3r = *(const uint4*)(pV + (J0) + oV3);                             \
    } while (0)

    f32x16 o0 = {}, o1 = {};
    float lsum = 0.0f;

    LOADREGS(0);                      // prologue: tile 0 in flight to regs

    for (int j0 = 0; j0 < 2048; j0 += 128) {
        __syncthreads();   // prior tile's fragment reads complete
        *(uint4*)(&Ks [dK0]) = k0r;                   // compiler inserts
        *(uint4*)(&Ks [dK1]) = k1r;                   // vmcnt waits
        *(uint4*)(&Ks [dK2]) = k2r;
        *(uint4*)(&Ks [dK3]) = k3r;
        *(uint4*)(&VTs[(0 * 256 + tid) * 8]) = v0r;
        *(uint4*)(&VTs[(1 * 256 + tid) * 8]) = v1r;
        *(uint4*)(&VTs[(2 * 256 + tid) * 8]) = v2r;
        *(uint4*)(&VTs[(3 * 256 + tid) * 8]) = v3r;
        if (j0 + 128 < 2048)
            LOADREGS(j0 + 128);       // next tile's loads fly under compute
        __syncthreads();   // LDS writes visible to all waves

        // S^T = K * Q^T: 4 stripes of 32 keys. A = K-frag (m=key lane&31,
        // ch = hi*8+16s), B = Q-frag (regs). C col = qrow, row = key.
        f32x16 st[4];
        #pragma unroll
        for (int t = 0; t < 4; t++) {
            int key = t * 32 + l31;
            f32x16 z = {};
            __builtin_amdgcn_s_setprio(1);
            #pragma unroll
            for (int s = 0; s < 4; s++) {
                int chunk = ((2 * s + hi) ^ (key & 7)) * 8;
                short8 kf = *(const short8*)(&Ks[key * 68 + chunk]);
                z = __builtin_amdgcn_mfma_f32_32x32x16_bf16(kf, qf[s], z, 0, 0, 0);
            }
            __builtin_amdgcn_s_setprio(0);
            st[t] = z;
        }

        // softmax fully in registers: X/Y[t][g] pack keys (t*32+g*8+4hi)+0..3
        // for qrow = l31 (bit-identical values to the old Ps path).
        u32 X[4][4], Y[4][4];
        #pragma unroll
        for (int t = 0; t < 4; t++)
            #pragma unroll
            for (int g = 0; g < 4; g++) {
                float p0 = __builtin_amdgcn_exp2f(st[t][4 * g + 0]);
                float p1 = __builtin_amdgcn_exp2f(st[t][4 * g + 1]);
                float p2 = __builtin_amdgcn_exp2f(st[t][4 * g + 2]);
                float p3 = __builtin_amdgcn_exp2f(st[t][4 * g + 3]);
                lsum += (p0 + p1) + (p2 + p3);
                X[t][g] = f2bf_trunc_u32(p0) | (f2bf_trunc_u32(p1) << 16);
                Y[t][g] = f2bf_trunc_u32(p2) | (f2bf_trunc_u32(p3) << 16);
            }

        // PV: O[qrow][ch] += P * V over 8 sixteen-key chunks c16 (keys
        // 16*c16..+15). VT's permuted key order ([0-3,8-11,4-7,12-15] per 16)
        // means B-chunk 2*c16+hi holds exactly keys {16c16+4hi+0..3,
        // 16c16+8+4hi+0..3} — the keys THIS lane's X/Y regs hold. A-frag is
        // lane-local and hi-independent: {X[t][2u],Y[t][2u],X[t][2u+1],
        // Y[t][2u+1]} with t=c16>>1, u=c16&1. No shuffles.
        #pragma unroll
        for (int c16 = 0; c16 < 8; ++c16) {
            const int t = c16 >> 1, u = c16 & 1;
            union { u32 u4[4]; short8 s8; } pk;
            pk.u4[0] = X[t][2 * u];        // keys 16c16+4hi+0,1
            pk.u4[1] = Y[t][2 * u];        // keys 16c16+4hi+2,3
            pk.u4[2] = X[t][2 * u + 1];    // keys 16c16+8+4hi+0,1
            pk.u4[3] = Y[t][2 * u + 1];    // keys 16c16+8+4hi+2,3
            const int kch = 2 * c16 + hi;             // VTs 8-u16 chunk
            short8 v0 = *(const short8*)(&VTs[l31 * 128 + ((kch ^ (l31 & 15)) * 8)]);
            short8 v1 = *(const short8*)(&VTs[(32 + l31) * 128 + ((kch ^ ((32 + l31) & 15)) * 8)]);
            __builtin_amdgcn_s_setprio(1);
            o0 = __builtin_amdgcn_mfma_f32_32x32x16_bf16(pk.s8, v0, o0, 0, 0, 0);
            o1 = __builtin_amdgcn_mfma_f32_32x32x16_bf16(pk.s8, v1, o1, 0, 0, 0);
            __builtin_amdgcn_s_setprio(0);
        }
    }
#undef LOADREGS

    // row-sum: lane holds all partials for qrow = lane&31 (S^T col) ->
    // one cross-half reduce, then broadcast per-reg via shfl.
    lsum += __shfl_xor(lsum, 32);
    float linv = 1.0f / lsum;

    size_t qrow0 = (size_t)qt * 128 + wid * 32;
    #pragma unroll
    for (int half = 0; half < 2; half++) {
        f32x16 o = half ? o1 : o0;
        #pragma unroll
        for (int reg = 0; reg < 16; reg++) {
            int qrow = (reg & 3) + 8 * (reg >> 2) + 4 * hi;   // C/D row (m74)
            float nv = o[reg] * __shfl(linv, qrow);
            Y[base + (qrow0 + qrow) * 1024 + half * 32 + l31] = f2bf(nv);
        }
    }
}

// ---------------------------------------------------------------------------
extern "C" void kernel_launch(void* const* d_in, const int* in_sizes, int n_in,
                              void* d_out, int out_size, void* d_ws, size_t ws_size,
                              hipStream_t stream)
{
    const float* x  = (const float*)d_in[0];
    const float* Wq = (const float*)d_in[1];
    const float* Wk = (const float*)d_in[2];
    const float* Wv = (const float*)d_in[3];
    const float* Wo = (const float*)d_in[4];
    float* out = (float*)d_out;

    char* ws = (char*)d_ws;
    u16*    xb    = (u16*)   (ws + (0ull  << 20));   // 8 MB
    u16*    WqkvT = (u16*)   (ws + (8ull  << 20));   // 6 MB stacked
    u16*    WoT   = (u16*)   (ws + (14ull << 20));   // 2 MB
    u16*    Qb    = (u16*)   (ws + (16ull << 20));   // 8 MB each
    u16*    Kb    = (u16*)   (ws + (24ull << 20));
    u16*    VTb   = (u16*)   (ws + (32ull << 20));   // V transposed per head
    u16*    Yb    = (u16*)   (ws + (40ull << 20));
    float2* tab   = (float2*)(ws + (48ull << 20));   // 512 KB rope table

    prep<<<dim3(32, 32, 9), dim3(32, 8), 0, stream>>>(
        x, xb, Wq, Wk, Wv, Wo,
        WqkvT, WqkvT + (1024ull * 1024), WqkvT + (2048ull * 1024), WoT, tab);
    gemm_qkv<<<dim3(48, 32), 256, 0, stream>>>(xb, WqkvT, tab, Qb, Kb, VTb);
    attn<<<dim3(32, 16), 256, 0, stream>>>(Qb, Kb, VTb, Yb);
    gemm_out<<<dim3(16, 64), 256, 0, stream>>>(Yb, WoT, out);
}